// Round 5
// baseline (164.213 us; speedup 1.0000x reference)
//
#include <hip/hip_runtime.h>
#include <hip/hip_bf16.h>

#define TT 4096
#define DD 64
#define HH 12
#define LAMAX 256
#define KT 32
#define NT 10      // tiles covering [q0-256, q0+64)
#define VS 36      // V^T row stride (shorts); 16-lane-phase bank model: conflict-free

typedef __attribute__((ext_vector_type(8))) short s8v;
typedef __attribute__((ext_vector_type(4))) short s4v;
typedef __attribute__((ext_vector_type(2))) short s2v;
typedef __attribute__((ext_vector_type(4))) float f4v;

static __device__ __forceinline__ unsigned pk2(float a, float b) {
  __hip_bfloat162 h = __float22bfloat162_rn(make_float2(a, b));
  unsigned u;
  __builtin_memcpy(&u, &h, sizeof(u));   // lo = a, hi = b
  return u;
}

static __device__ __forceinline__ s8v pack8(float4 a, float4 b) {
  union { unsigned u[4]; s8v s; } r;
  r.u[0] = pk2(a.x, a.y); r.u[1] = pk2(a.z, a.w);
  r.u[2] = pk2(b.x, b.y); r.u[3] = pk2(b.z, b.w);
  return r.s;
}

static __device__ __forceinline__ s8v pack8s(float4 a, float4 b, float s) {
  union { unsigned u[4]; s8v r; } o;
  o.u[0] = pk2(a.x * s, a.y * s); o.u[1] = pk2(a.z * s, a.w * s);
  o.u[2] = pk2(b.x * s, b.y * s); o.u[3] = pk2(b.z * s, b.w * s);
  return o.r;
}

static __device__ __forceinline__ f4v MFMA16(s4v a, s4v b, f4v c) {
#if defined(__has_builtin) && __has_builtin(__builtin_amdgcn_mfma_f32_16x16x16bf16_1k)
  return __builtin_amdgcn_mfma_f32_16x16x16bf16_1k(a, b, c, 0, 0, 0);
#else
  asm("v_mfma_f32_16x16x16_bf16 %0, %1, %2, %0\n\ts_nop 7\n\ts_nop 7"
      : "+v"(c) : "v"(a), "v"(b));
  return c;
#endif
}

// 64 q-rows/block, 4 waves x 16 rows. KT=32 key tiles, LDS dbuf (17.2 KB),
// 1 barrier/iter, T14 async-stage split. Grid 1536 = 6 blocks/CU, one generation.
__global__ __launch_bounds__(256, 6)
void lma_attn_kernel(const float* __restrict__ Q, const float* __restrict__ K,
                     const float* __restrict__ V, const int* __restrict__ laPtr,
                     float* __restrict__ out)
{
  __shared__ short k_lds[2][KT * 64];   // bf16 K [j][d], b128 XOR swizzle (slot^=j&7)
  __shared__ short vt_lds[2][64 * VS];  // bf16 V^T [d][j]

  const int tid  = threadIdx.x;
  const int lane = tid & 63;
  const int w    = tid >> 6;
  const int c    = lane & 15;
  const int g    = lane >> 4;

  // linear mapping (R1's — measured faster than XCD-chunk swizzle twice)
  const int bid = blockIdx.x;
  const int bh  = bid >> 6;
  const int q0  = (bid & 63) << 6;
  const int la  = laPtr[0];

  const size_t base = (size_t)bh * (TT * DD);
  const int rb    = q0 + w * 16;
  const int i_row = rb + c;

  // ---- Q fragment, pre-scaled by 1/sqrt(64)*log2(e) ----
  const float SCL = 0.125f * 1.44269504f;
  s8v qf[2];
  {
    const float* qp = Q + base + (size_t)i_row * DD + 8 * g;
    qf[0] = pack8s(*(const float4*)qp,        *(const float4*)(qp + 4),  SCL);
    qf[1] = pack8s(*(const float4*)(qp + 32), *(const float4*)(qp + 36), SCL);
  }

  // staging maps: K row kj (32 rows, 8 dims/thread), V row-pair vj0 (4 dims/thread)
  const int kj  = tid >> 3;           // 0..31
  const int kd0 = (tid & 7) << 3;     // 0..56
  const int vj0 = (tid & 15) << 1;    // 0..30
  const int vd0 = (tid >> 4) << 2;    // 0..60

  float4 kr0, kr1, vr0, vr1;
  auto stage_load = [&](int kj0) {
    const float* kp = K + base + (size_t)(kj0 + kj) * DD + kd0;
    kr0 = *(const float4*)kp; kr1 = *(const float4*)(kp + 4);
    const float* vp = V + base + (size_t)(kj0 + vj0) * DD + vd0;
    vr0 = *(const float4*)vp; vr1 = *(const float4*)(vp + DD);
  };
  auto stage_write = [&](int buf) {
    *(s8v*)&k_lds[buf][kj * 64 + (((tid & 7) ^ (kj & 7)) << 3)] = pack8(kr0, kr1);
    const float a0[4] = {vr0.x, vr0.y, vr0.z, vr0.w};
    const float a1[4] = {vr1.x, vr1.y, vr1.z, vr1.w};
    #pragma unroll
    for (int e = 0; e < 4; ++e) {
      unsigned pr = pk2(a0[e], a1[e]);
      s2v prv;
      __builtin_memcpy(&prv, &pr, sizeof(prv));
      *(s2v*)&vt_lds[buf][(vd0 + e) * VS + vj0] = prv;
    }
  };

  f4v acc[4] = {};     // out^T[d = 16dt+4g+r][q = c]
  float m2   = -1e30f; // running max (log2 domain)
  float lsum = 0.f;

  const int t0 = (q0 >= LAMAX) ? 0 : ((LAMAX - q0) >> 5);

  stage_load(q0 - LAMAX + (t0 << 5));
  stage_write(t0 & 1);
  __syncthreads();

  for (int t = t0; t < NT; ++t) {
    const int kj0 = q0 - LAMAX + (t << 5);
    if (t + 1 < NT) stage_load(kj0 + KT);   // issue next-tile loads early (T14)

    const short* kb = k_lds[t & 1];
    const short* vb = vt_lds[t & 1];

    // wave-uniform activity (each wave skips ~1 of 10 tiles)
    if ((kj0 <= rb + 15) && (kj0 + KT >= rb - la + 2)) {
      // ---- S^T = K * Q^T : 2 key-subtiles x K=64 ----
      f4v sa[2] = {};
      #pragma unroll
      for (int ch = 0; ch < 2; ++ch)
        #pragma unroll
        for (int ks = 0; ks < 2; ++ks) {
          s8v kf = *(const s8v*)&kb[(ks * 16 + c) * 64 + ((((ch << 2) + g) ^ (c & 7)) << 3)];
          sa[ks] = __builtin_amdgcn_mfma_f32_16x16x32_bf16(kf, qf[ch], sa[ks], 0, 0, 0);
        }

      // ---- mask (specialized) ----
      const bool needC = (kj0 + KT - 1 > rb);        // diagonal tile (wave-uniform)
      const bool needL = (kj0 < rb + 16 - la);       // left-edge tile
      const int jloR = i_row - la + 1;
      float p[2][4];
      #define MASKP(NC, NL)                                                \
        _Pragma("unroll")                                                  \
        for (int ks = 0; ks < 2; ++ks)                                     \
          _Pragma("unroll")                                                \
          for (int r = 0; r < 4; ++r) {                                    \
            float s = sa[ks][r];                                           \
            if (NC || NL) {                                                \
              const int jt = kj0 + ks * 16 + 4 * g + r;                    \
              bool ok = true;                                              \
              if (NC) ok = (jt <= i_row);                                  \
              if (NL) ok = ok && (jt >= jloR);                             \
              s = ok ? s : -1e30f;                                         \
            }                                                              \
            p[ks][r] = s;                                                  \
          }
      if (needC) { if (needL) { MASKP(true, true) } else { MASKP(true, false) } }
      else       { if (needL) { MASKP(false, true) } else { MASKP(false, false) } }
      #undef MASKP

      // ---- row max: 7-op tree + 2 shfl ----
      float tmax = fmaxf(fmaxf(fmaxf(p[0][0], p[0][1]), fmaxf(p[0][2], p[0][3])),
                         fmaxf(fmaxf(p[1][0], p[1][1]), fmaxf(p[1][2], p[1][3])));
      tmax = fmaxf(tmax, __shfl_xor(tmax, 16, 64));
      tmax = fmaxf(tmax, __shfl_xor(tmax, 32, 64));

      // ---- T13 defer-max ----
      if (!__all(tmax <= m2 + 8.0f)) {
        const float mn = fmaxf(m2, tmax);
        const float corr = __builtin_amdgcn_exp2f(m2 - mn);  // 0 on junk->real
        m2 = mn;
        lsum *= corr;
        #pragma unroll
        for (int dt = 0; dt < 4; ++dt) {
          acc[dt][0] *= corr; acc[dt][1] *= corr;
          acc[dt][2] *= corr; acc[dt][3] *= corr;
        }
      }

      // ---- exp2 + packed-pair convert ----
      float e[2][4];
      #pragma unroll
      for (int ks = 0; ks < 2; ++ks)
        #pragma unroll
        for (int r = 0; r < 4; ++r)
          e[ks][r] = __builtin_amdgcn_exp2f(p[ks][r] - m2);
      s4v pb[2];
      #pragma unroll
      for (int ks = 0; ks < 2; ++ks) {
        union { unsigned u[2]; s4v s; } pp;
        pp.u[0] = pk2(e[ks][0], e[ks][1]);
        pp.u[1] = pk2(e[ks][2], e[ks][3]);
        pb[ks] = pp.s;
      }

      // ---- PV: out^T += V^T * P^T (layout-matched, 0 shuffles) ----
      #pragma unroll
      for (int dt = 0; dt < 4; ++dt) {
        const int d = dt * 16 + c;
        #pragma unroll
        for (int sub = 0; sub < 2; ++sub) {
          s4v vf = *(const s4v*)&vb[d * VS + sub * 16 + 4 * g];
          acc[dt] = MFMA16(vf, pb[sub], acc[dt]);
        }
      }

      // ---- sum tree off critical path ----
      float ps = ((e[0][0] + e[0][1]) + (e[0][2] + e[0][3])) +
                 ((e[1][0] + e[1][1]) + (e[1][2] + e[1][3]));
      ps += __shfl_xor(ps, 16, 64);
      ps += __shfl_xor(ps, 32, 64);
      lsum += ps;
    }

    if (t + 1 < NT) stage_write((t + 1) & 1);   // write late (vmcnt wait here)
    __syncthreads();                            // single barrier per iteration
  }

  // ---- epilogue: lane owns one q-row; lanes g=0..3 tile a 64B line per dt ----
  const float inv = 1.f / lsum;
  float* op = out + ((size_t)(bh / HH) * TT + i_row) * (HH * DD) + (bh % HH) * DD + 4 * g;
  #pragma unroll
  for (int dt = 0; dt < 4; ++dt) {
    float4 o;
    o.x = acc[dt][0] * inv; o.y = acc[dt][1] * inv;
    o.z = acc[dt][2] * inv; o.w = acc[dt][3] * inv;
    *(float4*)(op + dt * 16) = o;
  }
}

extern "C" void kernel_launch(void* const* d_in, const int* in_sizes, int n_in,
                              void* d_out, int out_size, void* d_ws, size_t ws_size,
                              hipStream_t stream) {
  const float* q = (const float*)d_in[0];
  const float* k = (const float*)d_in[1];
  const float* v = (const float*)d_in[2];
  const int* la = (const int*)d_in[3];
  float* out = (float*)d_out;
  (void)in_sizes; (void)n_in; (void)out_size; (void)d_ws; (void)ws_size;

  dim3 grid(24 * 64);
  dim3 block(256);
  lma_attn_kernel<<<grid, block, 0, stream>>>(q, k, v, la, out);
}

// Round 13
// 130.746 us; speedup vs baseline: 1.2560x; 1.2560x over previous
//
#include <hip/hip_runtime.h>
#include <hip/hip_bf16.h>

#define TT 4096
#define DD 64
#define HH 12
#define LAMAX 256
#define KT 32
#define NT 12      // tiles covering [q0-256, q0+128)
#define VS 36      // V^T row stride (shorts)

typedef __attribute__((ext_vector_type(8))) short s8v;
typedef __attribute__((ext_vector_type(4))) short s4v;
typedef __attribute__((ext_vector_type(2))) short s2v;
typedef __attribute__((ext_vector_type(4))) float f4v;

static __device__ __forceinline__ unsigned pk2(float a, float b) {
  __hip_bfloat162 h = __float22bfloat162_rn(make_float2(a, b));
  unsigned u;
  __builtin_memcpy(&u, &h, sizeof(u));   // lo = a, hi = b
  return u;
}

static __device__ __forceinline__ s8v pack8(float4 a, float4 b) {
  union { unsigned u[4]; s8v s; } r;
  r.u[0] = pk2(a.x, a.y); r.u[1] = pk2(a.z, a.w);
  r.u[2] = pk2(b.x, b.y); r.u[3] = pk2(b.z, b.w);
  return r.s;
}

static __device__ __forceinline__ s8v pack8s(float4 a, float4 b, float s) {
  union { unsigned u[4]; s8v r; } o;
  o.u[0] = pk2(a.x * s, a.y * s); o.u[1] = pk2(a.z * s, a.w * s);
  o.u[2] = pk2(b.x * s, b.y * s); o.u[3] = pk2(b.z * s, b.w * s);
  return o.r;
}

static __device__ __forceinline__ f4v MFMA16(s4v a, s4v b, f4v c) {
#if defined(__has_builtin) && __has_builtin(__builtin_amdgcn_mfma_f32_16x16x16bf16_1k)
  return __builtin_amdgcn_mfma_f32_16x16x16bf16_1k(a, b, c, 0, 0, 0);
#else
  asm("v_mfma_f32_16x16x16_bf16 %0, %1, %2, %0\n\ts_nop 7\n\ts_nop 7"
      : "+v"(c) : "v"(a), "v"(b));
  return c;
#endif
}

// 128 q-rows/block, 8 waves x 16 rows, 512 threads. KT=32 key tiles, LDS dbuf
// (17.4 KB), 1 barrier/iter, T14 split, role-split staging (waves 0-3 K, 4-7 V).
// Grid 768 = 3 blocks/CU = 24 waves/CU; XCD-chunked mapping for L2 locality.
__global__ __launch_bounds__(512, 6)
void lma_attn_kernel(const float* __restrict__ Q, const float* __restrict__ K,
                     const float* __restrict__ V, const int* __restrict__ laPtr,
                     float* __restrict__ out)
{
  __shared__ short k_lds[2][KT * 64];   // bf16 K [j][d], b128 XOR swizzle (slot^=j&7)
  __shared__ short vt_lds[2][64 * VS];  // bf16 V^T [d][j]

  const int tid  = threadIdx.x;
  const int lane = tid & 63;
  const int w    = tid >> 6;          // 0..7
  const int c    = lane & 15;
  const int g    = lane >> 4;

  // XCD-chunked bijective swizzle: grid = 768 = 8 * 96 -> same-head adjacent
  // q-strips co-resident per XCD (overlapping K/V windows hit that XCD's L2).
  const int bid = blockIdx.x;
  const int wg  = (bid & 7) * 96 + (bid >> 3);
  const int bh  = wg >> 5;
  const int q0  = (wg & 31) << 7;     // 128-row strip
  const int la  = laPtr[0];

  const size_t base = (size_t)bh * (TT * DD);
  const int rb    = q0 + w * 16;      // wave's first row
  const int i_row = rb + c;

  // ---- Q fragment, pre-scaled by 1/sqrt(64)*log2(e) ----
  const float SCL = 0.125f * 1.44269504f;
  s8v qf[2];
  {
    const float* qp = Q + base + (size_t)i_row * DD + 8 * g;
    qf[0] = pack8s(*(const float4*)qp,        *(const float4*)(qp + 4),  SCL);
    qf[1] = pack8s(*(const float4*)(qp + 32), *(const float4*)(qp + 36), SCL);
  }

  // ---- role-split staging: waves 0-3 stage K tile, waves 4-7 stage V tile ----
  const bool kRole = (w < 4);
  const int st  = tid & 255;
  const int kj  = st >> 3;            // K row 0..31
  const int kd0 = (st & 7) << 3;      // K dim start
  const int vj0 = (st & 15) << 1;     // V row pair
  const int vd0 = (st >> 4) << 2;     // V dim start

  float4 r0, r1;
  auto stage_load = [&](int kj0) {
    if (kRole) {
      const float* kp = K + base + (size_t)(kj0 + kj) * DD + kd0;
      r0 = *(const float4*)kp; r1 = *(const float4*)(kp + 4);
    } else {
      const float* vp = V + base + (size_t)(kj0 + vj0) * DD + vd0;
      r0 = *(const float4*)vp; r1 = *(const float4*)(vp + DD);
    }
  };
  auto stage_write = [&](int buf) {
    if (kRole) {
      *(s8v*)&k_lds[buf][kj * 64 + (((st & 7) ^ (kj & 7)) << 3)] = pack8(r0, r1);
    } else {
      const float a0[4] = {r0.x, r0.y, r0.z, r0.w};
      const float a1[4] = {r1.x, r1.y, r1.z, r1.w};
      #pragma unroll
      for (int e = 0; e < 4; ++e) {
        unsigned pr = pk2(a0[e], a1[e]);
        s2v prv;
        __builtin_memcpy(&prv, &pr, sizeof(prv));
        *(s2v*)&vt_lds[buf][(vd0 + e) * VS + vj0] = prv;
      }
    }
  };

  f4v acc[4] = {};     // out^T[d = 16dt+4g+r][q = c]
  float m2   = -1e30f; // running max (log2 domain)
  float lsum = 0.f;

  const int t0 = (q0 >= LAMAX) ? 0 : ((LAMAX - q0) >> 5);

  stage_load(q0 - LAMAX + (t0 << 5));
  stage_write(t0 & 1);
  __syncthreads();

  for (int t = t0; t < NT; ++t) {
    const int kj0 = q0 - LAMAX + (t << 5);
    if (t + 1 < NT) stage_load(kj0 + KT);   // issue next-tile loads early (T14)

    const short* kb = k_lds[t & 1];
    const short* vb = vt_lds[t & 1];

    // wave-uniform activity (each wave active ~9-10 of 12 tiles)
    if ((kj0 <= rb + 15) && (kj0 + KT >= rb - la + 2)) {
      // ---- S^T = K * Q^T : 2 key-subtiles x K=64 ----
      f4v sa[2] = {};
      #pragma unroll
      for (int ch = 0; ch < 2; ++ch)
        #pragma unroll
        for (int ks = 0; ks < 2; ++ks) {
          s8v kf = *(const s8v*)&kb[(ks * 16 + c) * 64 + ((((ch << 2) + g) ^ (c & 7)) << 3)];
          sa[ks] = __builtin_amdgcn_mfma_f32_16x16x32_bf16(kf, qf[ch], sa[ks], 0, 0, 0);
        }

      // ---- mask (specialized per tile class, wave-uniform branches) ----
      const bool needC = (kj0 + KT - 1 > rb);
      const bool needL = (kj0 < rb + 16 - la);
      const int jloR = i_row - la + 1;
      float p[2][4];
      #define MASKP(NC, NL)                                                \
        _Pragma("unroll")                                                  \
        for (int ks = 0; ks < 2; ++ks)                                     \
          _Pragma("unroll")                                                \
          for (int r = 0; r < 4; ++r) {                                    \
            float s = sa[ks][r];                                           \
            if (NC || NL) {                                                \
              const int jt = kj0 + ks * 16 + 4 * g + r;                    \
              bool ok = true;                                              \
              if (NC) ok = (jt <= i_row);                                  \
              if (NL) ok = ok && (jt >= jloR);                             \
              s = ok ? s : -1e30f;                                         \
            }                                                              \
            p[ks][r] = s;                                                  \
          }
      if (needC) { if (needL) { MASKP(true, true) } else { MASKP(true, false) } }
      else       { if (needL) { MASKP(false, true) } else { MASKP(false, false) } }
      #undef MASKP

      // ---- row max: 7-op tree + 2 shfl ----
      float tmax = fmaxf(fmaxf(fmaxf(p[0][0], p[0][1]), fmaxf(p[0][2], p[0][3])),
                         fmaxf(fmaxf(p[1][0], p[1][1]), fmaxf(p[1][2], p[1][3])));
      tmax = fmaxf(tmax, __shfl_xor(tmax, 16, 64));
      tmax = fmaxf(tmax, __shfl_xor(tmax, 32, 64));

      // ---- T13 defer-max; corr=0 wipes any junk epoch per-row ----
      if (!__all(tmax <= m2 + 8.0f)) {
        const float mn = fmaxf(m2, tmax);
        const float corr = __builtin_amdgcn_exp2f(m2 - mn);
        m2 = mn;
        lsum *= corr;
        #pragma unroll
        for (int dt = 0; dt < 4; ++dt) {
          acc[dt][0] *= corr; acc[dt][1] *= corr;
          acc[dt][2] *= corr; acc[dt][3] *= corr;
        }
      }

      // ---- exp2 + packed-pair convert ----
      float e[2][4];
      #pragma unroll
      for (int ks = 0; ks < 2; ++ks)
        #pragma unroll
        for (int r = 0; r < 4; ++r)
          e[ks][r] = __builtin_amdgcn_exp2f(p[ks][r] - m2);
      s4v pb[2];
      #pragma unroll
      for (int ks = 0; ks < 2; ++ks) {
        union { unsigned u[2]; s4v s; } pp;
        pp.u[0] = pk2(e[ks][0], e[ks][1]);
        pp.u[1] = pk2(e[ks][2], e[ks][3]);
        pb[ks] = pp.s;
      }

      // ---- PV: out^T += V^T * P^T (layout-matched, 0 shuffles) ----
      #pragma unroll
      for (int dt = 0; dt < 4; ++dt) {
        const int d = dt * 16 + c;
        #pragma unroll
        for (int sub = 0; sub < 2; ++sub) {
          s4v vf = *(const s4v*)&vb[d * VS + sub * 16 + 4 * g];
          acc[dt] = MFMA16(vf, pb[sub], acc[dt]);
        }
      }

      // ---- sum tree off critical path ----
      float ps = ((e[0][0] + e[0][1]) + (e[0][2] + e[0][3])) +
                 ((e[1][0] + e[1][1]) + (e[1][2] + e[1][3]));
      ps += __shfl_xor(ps, 16, 64);
      ps += __shfl_xor(ps, 32, 64);
      lsum += ps;
    }

    if (t + 1 < NT) stage_write((t + 1) & 1);   // write late (vmcnt wait here)
    __syncthreads();                            // single barrier per iteration
  }

  // ---- epilogue: lane owns one q-row; non-temporal stores (out is write-once,
  //      keep it out of the K/V L2 working set) ----
  const float inv = 1.f / lsum;
  float* op = out + ((size_t)(bh / HH) * TT + i_row) * (HH * DD) + (bh % HH) * DD + 4 * g;
  #pragma unroll
  for (int dt = 0; dt < 4; ++dt) {
    f4v o;
    o[0] = acc[dt][0] * inv; o[1] = acc[dt][1] * inv;
    o[2] = acc[dt][2] * inv; o[3] = acc[dt][3] * inv;
    __builtin_nontemporal_store(o, (f4v*)(op + dt * 16));
  }
}

extern "C" void kernel_launch(void* const* d_in, const int* in_sizes, int n_in,
                              void* d_out, int out_size, void* d_ws, size_t ws_size,
                              hipStream_t stream) {
  const float* q = (const float*)d_in[0];
  const float* k = (const float*)d_in[1];
  const float* v = (const float*)d_in[2];
  const int* la = (const int*)d_in[3];
  float* out = (float*)d_out;
  (void)in_sizes; (void)n_in; (void)out_size; (void)d_ws; (void)ws_size;

  dim3 grid(24 * 32);   // 128-row q-strips; 3 blocks/CU, whole grid co-resident
  dim3 block(512);
  lma_attn_kernel<<<grid, block, 0, stream>>>(q, k, v, la, out);
}